// Round 5
// baseline (724.813 us; speedup 1.0000x reference)
//
#include <hip/hip_runtime.h>
#include <math.h>

#define NZ 10
#define NLENS 29
#define NPAIR 45
#define NUNIT 23
#define UB 8
#define SSTR 1028               // padded wave-slice stride (float2)
#define STR 520                 // ST row stride (float2), 513 used
#define PST (1024*520)          // ST plane stride (float2)

static __device__ __forceinline__ float2 cmulf(float2 a, float2 b){
    return make_float2(a.x*b.x - a.y*b.y, a.x*b.y + a.y*b.x);
}
#define SW(i) ((i) ^ (((i)>>5)&31))
#define WB() __builtin_amdgcn_wave_barrier()

static constexpr double PI2   = 6.283185307179586;
static constexpr double KD    = PI2/0.00051;            // 2*pi/lambda
static constexpr double F0D   = 1.0/(2.0*(3.6/1024.0)); // 1/(2*PS)
static constexpr double FSTEP = 2.0*F0D/1023.0;
static constexpr double IL2D  = (1.0/0.00051)*(1.0/0.00051);
static constexpr double TPPID = PI2*8.74;               // 2*pi*T_PROP

// per-wave redundant W fill (768 entries; benign identical-value race, no barrier)
static __device__ __forceinline__ void load_W_wave(float2* W, const float2* Wg, int t){
    #pragma unroll
    for (int i = 0; i < 12; ++i){ int idx = t + 64*i; W[SW(idx)] = Wg[idx]; }
}

template<bool INV>
static __device__ __forceinline__ void bf4(const float2 a[4], float2 w1, float2 w2, float2 w3, float2 o[4]){
    if (INV){ w1.y = -w1.y; w2.y = -w2.y; w3.y = -w3.y; }
    float2 a1 = cmulf(a[1], w1), a2 = cmulf(a[2], w2), a3 = cmulf(a[3], w3);
    float2 t0 = make_float2(a[0].x+a2.x, a[0].y+a2.y);
    float2 t1 = make_float2(a[0].x-a2.x, a[0].y-a2.y);
    float2 t2 = make_float2(a1.x+a3.x, a1.y+a3.y);
    float2 t3 = make_float2(a1.x-a3.x, a1.y-a3.y);
    o[0] = make_float2(t0.x+t2.x, t0.y+t2.y);
    o[2] = make_float2(t0.x-t2.x, t0.y-t2.y);
    if (!INV){
        o[1] = make_float2(t1.x + t3.y, t1.y - t3.x);
        o[3] = make_float2(t1.x - t3.y, t1.y + t3.x);
    } else {
        o[1] = make_float2(t1.x - t3.y, t1.y + t3.x);
        o[3] = make_float2(t1.x + t3.y, t1.y - t3.x);
    }
}
template<bool INV>
static __device__ __forceinline__ void bf4nt(const float2 a[4], float2 o[4]){
    float2 t0 = make_float2(a[0].x+a[2].x, a[0].y+a[2].y);
    float2 t1 = make_float2(a[0].x-a[2].x, a[0].y-a[2].y);
    float2 t2 = make_float2(a[1].x+a[3].x, a[1].y+a[3].y);
    float2 t3 = make_float2(a[1].x-a[3].x, a[1].y-a[3].y);
    o[0] = make_float2(t0.x+t2.x, t0.y+t2.y);
    o[2] = make_float2(t0.x-t2.x, t0.y-t2.y);
    if (!INV){
        o[1] = make_float2(t1.x + t3.y, t1.y - t3.x);
        o[3] = make_float2(t1.x - t3.y, t1.y + t3.x);
    } else {
        o[1] = make_float2(t1.x - t3.y, t1.y + t3.x);
        o[3] = make_float2(t1.x + t3.y, t1.y - t3.x);
    }
}

// ===== radix-16 1024-pt Stockham, ONE WAVE per FFT, wave-private LDS slice =====
static __device__ __forceinline__ void r16_load(const float2* B, int t, float2 a[4][4]){
    #pragma unroll
    for (int k = 0; k < 4; ++k)
        #pragma unroll
        for (int q = 0; q < 4; ++q)
            a[k][q] = B[SW(t + 64*k + 256*q)];
}
template<bool INV>
static __device__ __forceinline__ void r16_s14(const float2 a[4][4], const float2* W, float2 z[4][4]){
    float2 y[4][4];
    #pragma unroll
    for (int k = 0; k < 4; ++k) bf4nt<INV>(a[k], y[k]);
    #pragma unroll
    for (int i = 0; i < 4; ++i){
        float2 b[4] = { y[0][i], y[1][i], y[2][i], y[3][i] };
        bf4<INV>(b, W[SW(64*i)], W[SW(128*i)], W[SW(192*i)], z[i]);
    }
}
static __device__ __forceinline__ void r16_st1(float2* B, int t, const float2 z[4][4]){
    #pragma unroll
    for (int i = 0; i < 4; ++i)
        #pragma unroll
        for (int d = 0; d < 4; ++d)
            B[SW(16*t + i + 4*d)] = z[i][d];
}
template<bool INV>
static __device__ __forceinline__ void r16_s16_64(const float2 a[4][4], const float2* W, int t, float2 z[4][4]){
    int mt = t & 15;
    float2 y[4][4];
    float2 w1 = W[SW(16*mt)], w2 = W[SW(32*mt)], w3 = W[SW(48*mt)];
    #pragma unroll
    for (int k = 0; k < 4; ++k) bf4<INV>(a[k], w1, w2, w3, y[k]);
    #pragma unroll
    for (int n = 0; n < 4; ++n){
        int m2 = mt + 16*n;
        float2 b[4] = { y[0][n], y[1][n], y[2][n], y[3][n] };
        bf4<INV>(b, W[SW(4*m2)], W[SW(8*m2)], W[SW(12*m2)], z[n]);
    }
}
static __device__ __forceinline__ void r16_st2(float2* B, int t, const float2 z[4][4]){
    int base = 256*(t>>4) + (t&15);
    #pragma unroll
    for (int n = 0; n < 4; ++n)
        #pragma unroll
        for (int d = 0; d < 4; ++d)
            B[SW(base + 16*n + 64*d)] = z[n][d];
}
template<bool INV>
static __device__ __forceinline__ void r16_s256(const float2 a[4][4], const float2* W, int t, float2 z[4][4]){
    #pragma unroll
    for (int k = 0; k < 4; ++k){
        int j = t + 64*k;
        bf4<INV>(a[k], W[SW(j)], W[SW(2*j)], W[SW(3*j)], z[k]);
    }
}
static __device__ __forceinline__ void r16_st3(float2* B, int t, const float2 z[4][4]){
    #pragma unroll
    for (int k = 0; k < 4; ++k)
        #pragma unroll
        for (int d = 0; d < 4; ++d)
            B[SW(t + 64*k + 256*d)] = z[k][d];
}
// input a[k][q] = element t+64k+256q; output z[k][d] = element t+64k+256d
template<bool INV>
static __device__ void r16_fft_regs(float2* B, const float2* W, int t, float2 a[4][4], float2 z[4][4]){
    float2 b[4][4];
    r16_s14<INV>(a, W, z);
    WB(); r16_st1(B, t, z); WB();
    r16_load(B, t, b); r16_s16_64<INV>(b, W, t, z);
    WB(); r16_st2(B, t, z); WB();
    r16_load(B, t, b); r16_s256<INV>(b, W, t, z);
}

static __device__ __forceinline__ float2 expi_from_double(double ph){
    double t = ph * (1.0/PI2);
    t -= floor(t);
    float th = (float)(t * PI2);
    float s, c; sincosf(th, &s, &c);
    return make_float2(c, s);
}

// ---- prep: lens phase+aperture (sign-packed), masked-tF half transpose, twiddles ----
__global__ __launch_bounds__(256) void k_prep(const float* __restrict__ rlist,
        const float* __restrict__ xpos, const float* __restrict__ ypos,
        const float* __restrict__ tF, const float* __restrict__ dm,
        float* __restrict__ phiA, float* __restrict__ TMv, float2* __restrict__ Wg){
    __shared__ float Tt[32][33];
    int b = blockIdx.x, tid = threadIdx.x;
    if (b < 4096){
        int idx = b*256 + tid;
        int r = idx >> 10, c = idx & 1023;
        float x = (float)(-1.8 + c*(3.6/1023.0));
        float y = (float)(-1.8 + r*(3.6/1023.0));
        const float ca2 = (float)(0.165*0.165);
        float Ts = 0.f; int any = 0;
        for (int l = 0; l < NLENS; ++l){
            float dx = x - xpos[l], dy = y - ypos[l];
            float d2 = dx*dx + dy*dy;
            if (d2 <= ca2){
                float rr = rlist[l];
                Ts += rr - sqrtf(fmaxf(rr*rr - d2, 1e-12f));
                any = 1;
            }
        }
        int ap = any && (x*x + y*y) <= 0.81f;
        float phi = (float)(KD*(1.515 - 1.0)) * Ts;
        phiA[idx] = ap ? phi : -1.0f;
    } else if (b < 5120){
        int tb = b - 4096;
        int bx = tb & 31, by = tb >> 5;
        int tx = tid & 31, ty = tid >> 5;   // 32 x 8
        #pragma unroll
        for (int j = 0; j < 4; ++j){
            int r = by*32 + ty + 8*j, c = bx*32 + tx;
            float tv = tF[(size_t)r*1024 + c];
            float mv = dm[(size_t)r*1024 + c];
            Tt[ty+8*j][tx] = (mv > 0.f) ? tv : -1.0f;
        }
        __syncthreads();
        #pragma unroll
        for (int j = 0; j < 4; ++j){
            int c = bx*32 + ty + 8*j, r = by*32 + tx;
            if (c <= 512) TMv[(size_t)c*1024 + r] = Tt[tx][ty+8*j];
        }
    } else {
        int t = (b-5120)*256 + tid;   // 3 blocks -> 768 entries
        float a = (float)((double)t * (-PI2/1024.0));
        float s, c; sincosf(a, &s, &c);
        Wg[t] = make_float2(c, s);
    }
}

// ---- P1 (row): gen U1 rows -> fwd x-FFT -> write A[y][kx] rows coalesced ----
__global__ __launch_bounds__(256,4) void k_p1(const float* __restrict__ phiA,
        const float* __restrict__ defocus, float2* __restrict__ A,
        const float2* __restrict__ Wg, int zoff){
    __shared__ float2 buf[4*SSTR];
    __shared__ float2 W[768];
    int tid = threadIdx.x, zz = blockIdx.y;
    int w = tid >> 6, t = tid & 63;
    load_W_wave(W, Wg, t);
    int row = blockIdx.x*4 + w;
    float2* B = buf + w*SSTR;
    float zf = defocus[zoff + zz];
    float y  = (float)(-1.8 + row*(3.6/1023.0));
    const float KF = (float)KD;
    const float* pha = phiA + ((size_t)row << 10);
    float2 a[4][4], z[4][4];
    #pragma unroll
    for (int k = 0; k < 4; ++k)
        #pragma unroll
        for (int q = 0; q < 4; ++q){
            int idx = t + 64*k + 256*q;
            float x = (float)(-1.8 + idx*(3.6/1023.0));
            float v = pha[idx];
            float2 uu = make_float2(0.f, 0.f);
            if (v >= 0.f){
                float qq = x*x + y*y;
                float phi_in = (KF*qq) / (2.0f*zf);
                uu = expi_from_double((double)(phi_in + v));
            }
            a[k][q] = uu;
        }
    r16_fft_regs<false>(B, W, t, a, z);
    float2* Ar = A + ((size_t)zz << 20) + ((size_t)row << 10);
    #pragma unroll
    for (int k = 0; k < 4; ++k)
        #pragma unroll
        for (int d = 0; d < 4; ++d)
            Ar[t + 64*k + 256*d] = z[k][d];
}

// ---- P2 (col): stage cols of A, fwd y-FFT, *H(fly), inv y-FFT, stage-out -> Bo ----
__global__ __launch_bounds__(256,4) void k_p2(const float2* __restrict__ A,
        float2* __restrict__ Bo, const float2* __restrict__ Wg){
    __shared__ float2 buf[4*SSTR];
    __shared__ float2 W[768];
    int tid = threadIdx.x, bx = blockIdx.x, zz = blockIdx.y;
    int cb = ((bx & 7) << 5) | (bx >> 3);
    int c0 = cb*4;
    int w = tid >> 6, t = tid & 63;
    load_W_wave(W, Wg, t);
    const float2* Az = A + ((size_t)zz << 20);
    for (int it = 0; it < 16; ++it){
        int rr = it*64 + (tid>>2), cc = tid & 3;
        buf[cc*SSTR + SW(rr)] = Az[((size_t)rr << 10) + c0 + cc];
    }
    __syncthreads();
    int kx = c0 + w;
    float2* B = buf + w*SSTR;
    float2 a[4][4], z[4][4];
    r16_load(B, t, a);
    r16_fft_regs<false>(B, W, t, a, z);
    // H on the fly (column term wave-uniform)
    int cs = (kx + 512) & 1023;
    float fc  = (float)(-F0D + cs*FSTEP);
    float fc2 = __fmul_rn(fc, fc);
    const float il2f = (float)IL2D, pf = (float)TPPID;
    #pragma unroll
    for (int k = 0; k < 4; ++k)
        #pragma unroll
        for (int d = 0; d < 4; ++d){
            int j2 = t + 64*k + 256*d;
            int rs = (j2 + 512) & 1023;
            float fr  = (float)(-F0D + rs*FSTEP);
            float kz2 = __fsub_rn(__fsub_rn(il2f, fc2), __fmul_rn(fr, fr));
            float kzf = sqrtf(fmaxf(kz2, 0.f));
            float2 h  = expi_from_double((double)__fmul_rn(pf, kzf));
            z[k][d] = cmulf(z[k][d], h);
        }
    r16_fft_regs<true>(B, W, t, z, a);
    const float sc = 1.0f/1024.0f;
    #pragma unroll
    for (int k = 0; k < 4; ++k)
        #pragma unroll
        for (int d = 0; d < 4; ++d){ a[k][d].x *= sc; a[k][d].y *= sc; }
    WB(); r16_st3(B, t, a);
    __syncthreads();
    float2* Bz = Bo + ((size_t)zz << 20);
    for (int it = 0; it < 16; ++it){
        int rr = it*64 + (tid>>2), cc = tid & 3;
        Bz[((size_t)rr << 10) + c0 + cc] = buf[cc*SSTR + SW(rr)];
    }
}

// ---- P3 (row): inv x-FFT rows of Bo -> p=|u|^2, row sums, fwd x-FFT(p) -> A rows ----
__global__ __launch_bounds__(256,4) void k_p3(const float2* __restrict__ Bo,
        float2* __restrict__ A, float* __restrict__ sumPartz, const float2* __restrict__ Wg){
    __shared__ float2 buf[4*SSTR];
    __shared__ float2 W[768];
    int tid = threadIdx.x, zz = blockIdx.y;
    int w = tid >> 6, t = tid & 63;
    load_W_wave(W, Wg, t);
    int y = blockIdx.x*4 + w;
    float2* B = buf + w*SSTR;
    const float2* Br = Bo + ((size_t)zz << 20) + ((size_t)y << 10);
    float2 a[4][4], z[4][4];
    #pragma unroll
    for (int k = 0; k < 4; ++k)
        #pragma unroll
        for (int q = 0; q < 4; ++q)
            a[k][q] = Br[t + 64*k + 256*q];
    r16_fft_regs<true>(B, W, t, a, z);
    const float s2 = (1.0f/1024.0f)*(1.0f/1024.0f);
    float lsum = 0.f;
    #pragma unroll
    for (int k = 0; k < 4; ++k)
        #pragma unroll
        for (int d = 0; d < 4; ++d){
            float2 u = z[k][d];
            float p = (u.x*u.x + u.y*u.y) * s2;
            a[k][d] = make_float2(p, 0.f);
            lsum += p;
        }
    for (int o = 32; o > 0; o >>= 1) lsum += __shfl_down(lsum, o, 64);
    if (t == 0) sumPartz[zz*1024 + y] = lsum;
    WB();
    r16_fft_regs<false>(B, W, t, a, z);
    float2* Ar = A + ((size_t)zz << 20) + ((size_t)y << 10);
    #pragma unroll
    for (int k = 0; k < 4; ++k)
        #pragma unroll
        for (int d = 0; d < 4; ++d)
            Ar[t + 64*k + 256*d] = z[k][d];
}

// ---- P4 (col, kx<=512): stage cols of A, fwd y-FFT, 1/sum, diag, stage-out ST rows ----
__global__ __launch_bounds__(256,4) void k_p4(const float2* __restrict__ A,
        float2* __restrict__ ST, const float* __restrict__ sumPartz,
        const float* __restrict__ TMv, float* __restrict__ dpartz,
        const float2* __restrict__ Wg){
    __shared__ float2 buf[4*SSTR];
    __shared__ float2 W[768];
    int tid = threadIdx.x, bx = blockIdx.x, zz = blockIdx.y;
    int c0 = bx*4;
    int w = tid >> 6, t = tid & 63;
    load_W_wave(W, Wg, t);
    const float2* Az = A + ((size_t)zz << 20);
    for (int it = 0; it < 16; ++it){
        int rr = it*64 + (tid>>2), cc = tid & 3;
        int kxc = c0 + cc;
        buf[cc*SSTR + SW(rr)] = (kxc <= 512) ? Az[((size_t)rr << 10) + kxc]
                                             : make_float2(0.f, 0.f);
    }
    // per-wave redundant total-sum reduction (overlaps staging latency)
    double sd = 0.0;
    for (int i = t; i < 1024; i += 64) sd += (double)sumPartz[zz*1024 + i];
    for (int o = 32; o > 0; o >>= 1) sd += __shfl_down(sd, o, 64);
    sd = __shfl(sd, 0, 64);
    float inv = (float)(1.0/sd);
    __syncthreads();
    int kx = c0 + w;
    float2* B = buf + w*SSTR;
    float2 a[4][4], z[4][4];
    r16_load(B, t, a);
    r16_fft_regs<false>(B, W, t, a, z);
    const float* TMc = TMv + ((size_t)kx << 10);
    const float nrm = 1.0f/1048576.0f;
    float dacc = 0.f;
    #pragma unroll
    for (int k = 0; k < 4; ++k)
        #pragma unroll
        for (int d = 0; d < 4; ++d){
            float2 s = z[k][d]; s.x *= inv; s.y *= inv; z[k][d] = s;
            if (kx <= 512){
                float tmv = TMc[t + 64*k + 256*d];
                if (tmv >= 0.f){
                    float dff = (s.x*s.x + s.y*s.y - tmv) * nrm;
                    dacc += dff * dff;
                }
            }
        }
    for (int o = 32; o > 0; o >>= 1) dacc += __shfl_down(dacc, o, 64);
    WB(); r16_st3(B, t, z);
    __syncthreads();
    float2* STz = ST + (size_t)zz*PST;
    for (int it = 0; it < 16; ++it){
        int rr = it*64 + (tid>>2), cc = tid & 3;
        int kxc = c0 + cc;
        if (kxc <= 512)
            STz[(size_t)rr*STR + kxc] = buf[cc*SSTR + SW(rr)];
    }
    if (t == 0 && kx <= 512){
        float wgt = (kx == 0 || kx == 512) ? 1.f : 2.f;
        dpartz[zz*1024 + kx] = dacc * wgt;
    }
}

static __device__ __forceinline__ void pair_of(int p, int& a, int& b){
    int i = 0, c = NZ-1;
    while (p >= c){ p -= c; ++i; --c; }
    a = i; b = i + 1 + p;
}

// ---- pairA (row): G rows (Hermitian mirror in kx), inv kx-FFT, write U[ky][x'] ----
__global__ __launch_bounds__(256,4) void k_pairA(const float2* __restrict__ ST,
        float2* __restrict__ U, int ubase, const float2* __restrict__ Wg){
    __shared__ float2 buf[4*SSTR];
    __shared__ float2 W[768];
    int tid = threadIdx.x, ug = blockIdx.y;
    int w = tid >> 6, t = tid & 63;
    load_W_wave(W, Wg, t);
    int ky = blockIdx.x*4 + w;
    int my = (1024 - ky) & 1023;
    float2* B = buf + w*SSTR;
    int u = ubase + ug;
    int pa = 2*u, pb = (2*u+1 < NPAIR) ? (2*u+1) : (NPAIR-1);
    int i1, i2, j1, j2;
    pair_of(pa, i1, i2); pair_of(pb, j1, j2);
    const float2* A1 = ST + (size_t)i1*PST + (size_t)ky*STR;
    const float2* A2 = ST + (size_t)i2*PST + (size_t)ky*STR;
    const float2* B1 = ST + (size_t)j1*PST + (size_t)ky*STR;
    const float2* B2 = ST + (size_t)j2*PST + (size_t)ky*STR;
    const float2* A1m = ST + (size_t)i1*PST + (size_t)my*STR;
    const float2* A2m = ST + (size_t)i2*PST + (size_t)my*STR;
    const float2* B1m = ST + (size_t)j1*PST + (size_t)my*STR;
    const float2* B2m = ST + (size_t)j2*PST + (size_t)my*STR;
    float2 a[4][4], z[4][4];
    #pragma unroll
    for (int k = 0; k < 4; ++k)
        #pragma unroll
        for (int q = 0; q < 4; ++q){
            int idx = t + 64*k + 256*q;
            float2 g1, g2;
            if (idx <= 512){
                float2 x1 = A1[idx], y1 = A2[idx], x2 = B1[idx], y2 = B2[idx];
                g1 = make_float2(x1.x*y1.x + x1.y*y1.y, x1.x*y1.y - x1.y*y1.x);
                g2 = make_float2(x2.x*y2.x + x2.y*y2.y, x2.x*y2.y - x2.y*y2.x);
            } else {
                int m = 1024 - idx;
                float2 x1 = A1m[m], y1 = A2m[m], x2 = B1m[m], y2 = B2m[m];
                // G(ky,idx) = conj(G(my,m)) = x*conj(y) form
                g1 = make_float2(x1.x*y1.x + x1.y*y1.y, x1.y*y1.x - x1.x*y1.y);
                g2 = make_float2(x2.x*y2.x + x2.y*y2.y, x2.y*y2.x - x2.x*y2.y);
            }
            a[k][q] = make_float2(g1.x - g2.y, g1.y + g2.x);
        }
    r16_fft_regs<true>(B, W, t, a, z);
    const float sc = 1.0f/1024.0f;
    float2* Up = U + ((size_t)ug << 20) + ((size_t)ky << 10);
    #pragma unroll
    for (int k = 0; k < 4; ++k)
        #pragma unroll
        for (int d = 0; d < 4; ++d){
            float2 v = z[k][d];
            Up[t + 64*k + 256*d] = make_float2(v.x*sc, v.y*sc);
        }
}

// ---- pairB (col): stage cols of U, inv ky-FFT, |Re|,|Im|, per-column lse partials ----
__global__ __launch_bounds__(256,4) void k_pairB(const float2* __restrict__ U,
        float2* __restrict__ lsePart, int ubase, const float2* __restrict__ Wg){
    __shared__ float2 buf[4*SSTR];
    __shared__ float2 W[768];
    int tid = threadIdx.x, bx = blockIdx.x, ug = blockIdx.y;
    int cb = ((bx & 7) << 5) | (bx >> 3);
    int c0 = cb*4;
    int w = tid >> 6, t = tid & 63;
    int u = ubase + ug;
    load_W_wave(W, Wg, t);
    const float2* Up = U + ((size_t)ug << 20);
    for (int it = 0; it < 16; ++it){
        int rr = it*64 + (tid>>2), cc = tid & 3;
        buf[cc*SSTR + SW(rr)] = Up[((size_t)rr << 10) + c0 + cc];
    }
    __syncthreads();
    float2* B = buf + w*SSTR;
    float2 a[4][4], z[4][4];
    r16_load(B, t, a);
    r16_fft_regs<true>(B, W, t, a, z);
    const float sc = 1.0f/1024.0f;
    float m1 = -1.f, m2 = -1.f;
    #pragma unroll
    for (int k = 0; k < 4; ++k)
        #pragma unroll
        for (int d = 0; d < 4; ++d){
            float c1 = fabsf(z[k][d].x)*sc, c2 = fabsf(z[k][d].y)*sc;
            z[k][d] = make_float2(c1, c2);
            m1 = fmaxf(m1, c1); m2 = fmaxf(m2, c2);
        }
    for (int o = 32; o > 0; o >>= 1){
        m1 = fmaxf(m1, __shfl_down(m1, o, 64));
        m2 = fmaxf(m2, __shfl_down(m2, o, 64));
    }
    float M1 = __shfl(m1, 0, 64), M2 = __shfl(m2, 0, 64);
    float s1 = 0.f, s2 = 0.f;
    #pragma unroll
    for (int k = 0; k < 4; ++k)
        #pragma unroll
        for (int d = 0; d < 4; ++d){
            s1 += expf((z[k][d].x - M1) * 100.0f);
            s2 += expf((z[k][d].y - M2) * 100.0f);
        }
    for (int o = 32; o > 0; o >>= 1){
        s1 += __shfl_down(s1, o, 64);
        s2 += __shfl_down(s2, o, 64);
    }
    if (t == 0){
        int xp = c0 + w;
        lsePart[(size_t)(2*u)*1024 + xp] = make_float2(M1, s1);
        if (2*u+1 < NPAIR)
            lsePart[(size_t)(2*u+1)*1024 + xp] = make_float2(M2, s2);
    }
}

// ---- final: 10 diag sums (513 partials) + 45 off (1024 partial LSEs) ----
__global__ __launch_bounds__(256) void k_final(const float* __restrict__ dpart,
        const float2* __restrict__ lsePart, float* __restrict__ out){
    __shared__ double dred[4];
    __shared__ float fred[4];
    int b = blockIdx.x, tid = threadIdx.x;
    if (b < NZ){
        double s = (double)dpart[b*1024 + tid] + (double)dpart[b*1024 + 256 + tid];
        if (tid == 0) s += (double)dpart[b*1024 + 512];
        for (int o = 32; o > 0; o >>= 1) s += __shfl_down(s, o, 64);
        if ((tid & 63) == 0) dred[tid >> 6] = s;
        __syncthreads();
        if (tid == 0) out[b] = (float)(dred[0]+dred[1]+dred[2]+dred[3]);
    } else {
        int p = b - NZ;
        const float2* lp = lsePart + (size_t)p*1024;
        float2 v[4]; float m = -1e30f;
        #pragma unroll
        for (int c = 0; c < 4; ++c){ v[c] = lp[tid + 256*c]; m = fmaxf(m, v[c].x); }
        for (int o = 32; o > 0; o >>= 1) m = fmaxf(m, __shfl_down(m, o, 64));
        if ((tid & 63) == 0) fred[tid >> 6] = m;
        __syncthreads();
        float M = fmaxf(fmaxf(fred[0], fred[1]), fmaxf(fred[2], fred[3]));
        double s = 0.0;
        #pragma unroll
        for (int c = 0; c < 4; ++c)
            s += (double)v[c].y * (double)expf((v[c].x - M)*100.0f);
        for (int o = 32; o > 0; o >>= 1) s += __shfl_down(s, o, 64);
        if ((tid & 63) == 0) dred[tid >> 6] = s;
        __syncthreads();
        if (tid == 0)
            out[NZ + p] = (float)(30.0*(double)M + 0.3*log(dred[0]+dred[1]+dred[2]+dred[3]));
    }
}

extern "C" void kernel_launch(void* const* d_in, const int* in_sizes, int n_in,
                              void* d_out, int out_size, void* d_ws, size_t ws_size,
                              hipStream_t stream){
    const float* rlist   = (const float*)d_in[0];
    const float* xpos    = (const float*)d_in[1];
    const float* ypos    = (const float*)d_in[2];
    const float* defocus = (const float*)d_in[3];
    const float* tF      = (const float*)d_in[4];
    const float* dmask   = (const float*)d_in[5];
    float* out = (float*)d_out;

    char* ws = (char*)d_ws;
    float2* ST   = (float2*)(ws);                    // 10 half planes, stride 520: 42,598,400 B
    float2* A    = (float2*)(ws + 42598400);         // 5 full planes: 41,943,040
    float2* Bst  = (float2*)(ws + 84541440);         // 5 full planes: 41,943,040
    float*  phiA = (float*) (ws + 126484480);        // 4 MiB
    float*  TMv  = (float*) (ws + 130678784);        // 513*1024*4 = 2,101,248
    char*   tail = ws + 132780032;
    float*  sumPart = (float*) (tail);               // 40,960
    float*  dpart   = (float*) (tail + 40960);       // 40,960
    float2* lsePart = (float2*)(tail + 81920);       // 368,640
    float2* Wg      = (float2*)(tail + 450560);      // 6,144 (end 133,236,736)
    float2* U       = (float2*)(ws + 42598400);      // UB*8 MiB, overlays A/Bst (dead)

    k_prep<<<5123, 256, 0, stream>>>(rlist, xpos, ypos, tF, dmask, phiA, TMv, Wg);
    for (int bz = 0; bz < 2; ++bz){
        int zoff = bz*5;
        k_p1<<<dim3(256, 5), 256, 0, stream>>>(phiA, defocus, A, Wg, zoff);
        k_p2<<<dim3(256, 5), 256, 0, stream>>>(A, Bst, Wg);
        k_p3<<<dim3(256, 5), 256, 0, stream>>>(Bst, A, sumPart + zoff*1024, Wg);
        k_p4<<<dim3(129, 5), 256, 0, stream>>>(A, ST + (size_t)zoff*PST,
                sumPart + zoff*1024, TMv, dpart + zoff*1024, Wg);
    }
    for (int g = 0; g < NUNIT; g += UB){
        int cnt = (NUNIT - g < UB) ? (NUNIT - g) : UB;
        k_pairA<<<dim3(256, cnt), 256, 0, stream>>>(ST, U, g, Wg);
        k_pairB<<<dim3(256, cnt), 256, 0, stream>>>(U, lsePart, g, Wg);
    }
    k_final<<<NZ + NPAIR, 256, 0, stream>>>(dpart, lsePart, out);
}

// Round 6
// 668.880 us; speedup vs baseline: 1.0836x; 1.0836x over previous
//
#include <hip/hip_runtime.h>
#include <math.h>

#define NZ 10
#define NLENS 29
#define NPAIR 45
#define NUNIT 23
#define SSTR 1028               // padded wave-slice stride (float2)

static __device__ __forceinline__ float2 cmulf(float2 a, float2 b){
    return make_float2(a.x*b.x - a.y*b.y, a.x*b.y + a.y*b.x);
}
#define SW(i) ((i) ^ (((i)>>5)&31))
#define WB() __builtin_amdgcn_wave_barrier()

static constexpr double PI2   = 6.283185307179586;
static constexpr double KD    = PI2/0.00051;            // 2*pi/lambda
static constexpr double F0D   = 1.0/(2.0*(3.6/1024.0)); // 1/(2*PS)
static constexpr double FSTEP = 2.0*F0D/1023.0;
static constexpr double IL2D  = (1.0/0.00051)*(1.0/0.00051);
static constexpr double TPPID = PI2*8.74;               // 2*pi*T_PROP

// per-wave redundant W fill (768 entries; benign identical-value race, no barrier)
static __device__ __forceinline__ void load_W_wave(float2* W, const float2* Wg, int t){
    #pragma unroll
    for (int i = 0; i < 12; ++i){ int idx = t + 64*i; W[SW(idx)] = Wg[idx]; }
}

template<bool INV>
static __device__ __forceinline__ void bf4(const float2 a[4], float2 w1, float2 w2, float2 w3, float2 o[4]){
    if (INV){ w1.y = -w1.y; w2.y = -w2.y; w3.y = -w3.y; }
    float2 a1 = cmulf(a[1], w1), a2 = cmulf(a[2], w2), a3 = cmulf(a[3], w3);
    float2 t0 = make_float2(a[0].x+a2.x, a[0].y+a2.y);
    float2 t1 = make_float2(a[0].x-a2.x, a[0].y-a2.y);
    float2 t2 = make_float2(a1.x+a3.x, a1.y+a3.y);
    float2 t3 = make_float2(a1.x-a3.x, a1.y-a3.y);
    o[0] = make_float2(t0.x+t2.x, t0.y+t2.y);
    o[2] = make_float2(t0.x-t2.x, t0.y-t2.y);
    if (!INV){
        o[1] = make_float2(t1.x + t3.y, t1.y - t3.x);
        o[3] = make_float2(t1.x - t3.y, t1.y + t3.x);
    } else {
        o[1] = make_float2(t1.x - t3.y, t1.y + t3.x);
        o[3] = make_float2(t1.x + t3.y, t1.y - t3.x);
    }
}
template<bool INV>
static __device__ __forceinline__ void bf4nt(const float2 a[4], float2 o[4]){
    float2 t0 = make_float2(a[0].x+a[2].x, a[0].y+a[2].y);
    float2 t1 = make_float2(a[0].x-a[2].x, a[0].y-a[2].y);
    float2 t2 = make_float2(a[1].x+a[3].x, a[1].y+a[3].y);
    float2 t3 = make_float2(a[1].x-a[3].x, a[1].y-a[3].y);
    o[0] = make_float2(t0.x+t2.x, t0.y+t2.y);
    o[2] = make_float2(t0.x-t2.x, t0.y-t2.y);
    if (!INV){
        o[1] = make_float2(t1.x + t3.y, t1.y - t3.x);
        o[3] = make_float2(t1.x - t3.y, t1.y + t3.x);
    } else {
        o[1] = make_float2(t1.x - t3.y, t1.y + t3.x);
        o[3] = make_float2(t1.x + t3.y, t1.y - t3.x);
    }
}

// ===== radix-16 1024-pt Stockham, ONE WAVE per FFT, wave-private LDS slice =====
static __device__ __forceinline__ void r16_load(const float2* B, int t, float2 a[4][4]){
    #pragma unroll
    for (int k = 0; k < 4; ++k)
        #pragma unroll
        for (int q = 0; q < 4; ++q)
            a[k][q] = B[SW(t + 64*k + 256*q)];
}
template<bool INV>
static __device__ __forceinline__ void r16_s14(const float2 a[4][4], const float2* W, float2 z[4][4]){
    float2 y[4][4];
    #pragma unroll
    for (int k = 0; k < 4; ++k) bf4nt<INV>(a[k], y[k]);
    #pragma unroll
    for (int i = 0; i < 4; ++i){
        float2 b[4] = { y[0][i], y[1][i], y[2][i], y[3][i] };
        bf4<INV>(b, W[SW(64*i)], W[SW(128*i)], W[SW(192*i)], z[i]);
    }
}
static __device__ __forceinline__ void r16_st1(float2* B, int t, const float2 z[4][4]){
    #pragma unroll
    for (int i = 0; i < 4; ++i)
        #pragma unroll
        for (int d = 0; d < 4; ++d)
            B[SW(16*t + i + 4*d)] = z[i][d];
}
template<bool INV>
static __device__ __forceinline__ void r16_s16_64(const float2 a[4][4], const float2* W, int t, float2 z[4][4]){
    int mt = t & 15;
    float2 y[4][4];
    float2 w1 = W[SW(16*mt)], w2 = W[SW(32*mt)], w3 = W[SW(48*mt)];
    #pragma unroll
    for (int k = 0; k < 4; ++k) bf4<INV>(a[k], w1, w2, w3, y[k]);
    #pragma unroll
    for (int n = 0; n < 4; ++n){
        int m2 = mt + 16*n;
        float2 b[4] = { y[0][n], y[1][n], y[2][n], y[3][n] };
        bf4<INV>(b, W[SW(4*m2)], W[SW(8*m2)], W[SW(12*m2)], z[n]);
    }
}
static __device__ __forceinline__ void r16_st2(float2* B, int t, const float2 z[4][4]){
    int base = 256*(t>>4) + (t&15);
    #pragma unroll
    for (int n = 0; n < 4; ++n)
        #pragma unroll
        for (int d = 0; d < 4; ++d)
            B[SW(base + 16*n + 64*d)] = z[n][d];
}
template<bool INV>
static __device__ __forceinline__ void r16_s256(const float2 a[4][4], const float2* W, int t, float2 z[4][4]){
    #pragma unroll
    for (int k = 0; k < 4; ++k){
        int j = t + 64*k;
        bf4<INV>(a[k], W[SW(j)], W[SW(2*j)], W[SW(3*j)], z[k]);
    }
}
static __device__ __forceinline__ void r16_st3(float2* B, int t, const float2 z[4][4]){
    #pragma unroll
    for (int k = 0; k < 4; ++k)
        #pragma unroll
        for (int d = 0; d < 4; ++d)
            B[SW(t + 64*k + 256*d)] = z[k][d];
}
// input a[k][q] = element t+64k+256q; output z[k][d] = element t+64k+256d
template<bool INV>
static __device__ void r16_fft_regs(float2* B, const float2* W, int t, float2 a[4][4], float2 z[4][4]){
    float2 b[4][4];
    r16_s14<INV>(a, W, z);
    WB(); r16_st1(B, t, z); WB();
    r16_load(B, t, b); r16_s16_64<INV>(b, W, t, z);
    WB(); r16_st2(B, t, z); WB();
    r16_load(B, t, b); r16_s256<INV>(b, W, t, z);
}

static __device__ __forceinline__ float2 expi_from_double(double ph){
    double t = ph * (1.0/PI2);
    t -= floor(t);
    float th = (float)(t * PI2);
    float s, c; sincosf(th, &s, &c);
    return make_float2(c, s);
}

// ---- prep: lens phase+aperture (sign-packed), masked-tF half transpose, twiddles ----
__global__ __launch_bounds__(256) void k_prep(const float* __restrict__ rlist,
        const float* __restrict__ xpos, const float* __restrict__ ypos,
        const float* __restrict__ tF, const float* __restrict__ dm,
        float* __restrict__ phiA, float* __restrict__ TMv, float2* __restrict__ Wg){
    __shared__ float Tt[32][33];
    int b = blockIdx.x, tid = threadIdx.x;
    if (b < 4096){
        int idx = b*256 + tid;
        int r = idx >> 10, c = idx & 1023;
        float x = (float)(-1.8 + c*(3.6/1023.0));
        float y = (float)(-1.8 + r*(3.6/1023.0));
        const float ca2 = (float)(0.165*0.165);
        float Ts = 0.f; int any = 0;
        for (int l = 0; l < NLENS; ++l){
            float dx = x - xpos[l], dy = y - ypos[l];
            float d2 = dx*dx + dy*dy;
            if (d2 <= ca2){
                float rr = rlist[l];
                Ts += rr - sqrtf(fmaxf(rr*rr - d2, 1e-12f));
                any = 1;
            }
        }
        int ap = any && (x*x + y*y) <= 0.81f;
        float phi = (float)(KD*(1.515 - 1.0)) * Ts;
        phiA[idx] = ap ? phi : -1.0f;
    } else if (b < 5120){
        int tb = b - 4096;
        int bx = tb & 31, by = tb >> 5;
        int tx = tid & 31, ty = tid >> 5;   // 32 x 8
        #pragma unroll
        for (int j = 0; j < 4; ++j){
            int r = by*32 + ty + 8*j, c = bx*32 + tx;
            float tv = tF[(size_t)r*1024 + c];
            float mv = dm[(size_t)r*1024 + c];
            Tt[ty+8*j][tx] = (mv > 0.f) ? tv : -1.0f;
        }
        __syncthreads();
        #pragma unroll
        for (int j = 0; j < 4; ++j){
            int c = bx*32 + ty + 8*j, r = by*32 + tx;
            if (c <= 512) TMv[(size_t)c*1024 + r] = Tt[tx][ty+8*j];
        }
    } else {
        int t = (b-5120)*256 + tid;   // 3 blocks -> 768 entries
        float a = (float)((double)t * (-PI2/1024.0));
        float s, c; sincosf(a, &s, &c);
        Wg[t] = make_float2(c, s);
    }
}

// ---- P1 (row): gen U1 rows -> fwd x-FFT -> write S[y][kx] rows coalesced ----
__global__ __launch_bounds__(256,4) void k_p1(const float* __restrict__ phiA,
        const float* __restrict__ defocus, float2* __restrict__ S,
        const float2* __restrict__ Wg){
    __shared__ float2 buf[4*SSTR];
    __shared__ float2 W[768];
    int tid = threadIdx.x, zz = blockIdx.y;
    int w = tid >> 6, t = tid & 63;
    load_W_wave(W, Wg, t);
    int row = blockIdx.x*4 + w;
    float2* B = buf + w*SSTR;
    float zf = defocus[zz];
    float y  = (float)(-1.8 + row*(3.6/1023.0));
    const float KF = (float)KD;
    const float* pha = phiA + ((size_t)row << 10);
    float2 a[4][4], z[4][4];
    #pragma unroll
    for (int k = 0; k < 4; ++k)
        #pragma unroll
        for (int q = 0; q < 4; ++q){
            int idx = t + 64*k + 256*q;
            float x = (float)(-1.8 + idx*(3.6/1023.0));
            float v = pha[idx];
            float2 uu = make_float2(0.f, 0.f);
            if (v >= 0.f){
                float qq = x*x + y*y;
                float phi_in = (KF*qq) / (2.0f*zf);
                uu = expi_from_double((double)(phi_in + v));
            }
            a[k][q] = uu;
        }
    r16_fft_regs<false>(B, W, t, a, z);
    float2* Sr = S + ((size_t)zz << 20) + ((size_t)row << 10);
    #pragma unroll
    for (int k = 0; k < 4; ++k)
        #pragma unroll
        for (int d = 0; d < 4; ++d)
            Sr[t + 64*k + 256*d] = z[k][d];
}

// ---- P2 (col, IN-PLACE): stage cols, fwd y-FFT, *H(fly), inv y-FFT, stage-out ----
__global__ __launch_bounds__(256,4) void k_p2(float2* __restrict__ S,
        const float2* __restrict__ Wg){
    __shared__ float2 buf[4*SSTR];
    __shared__ float2 W[768];
    int tid = threadIdx.x, bx = blockIdx.x, zz = blockIdx.y;
    int cb = ((bx & 7) << 5) | (bx >> 3);
    int c0 = cb*4;
    int w = tid >> 6, t = tid & 63;
    load_W_wave(W, Wg, t);
    float2* Sz = S + ((size_t)zz << 20);
    for (int it = 0; it < 16; ++it){
        int rr = it*64 + (tid>>2), cc = tid & 3;
        buf[cc*SSTR + SW(rr)] = Sz[((size_t)rr << 10) + c0 + cc];
    }
    __syncthreads();
    int kx = c0 + w;
    float2* B = buf + w*SSTR;
    float2 a[4][4], z[4][4];
    r16_load(B, t, a);
    r16_fft_regs<false>(B, W, t, a, z);
    // H on the fly (column term wave-uniform)
    int cs = (kx + 512) & 1023;
    float fc  = (float)(-F0D + cs*FSTEP);
    float fc2 = __fmul_rn(fc, fc);
    const float il2f = (float)IL2D, pf = (float)TPPID;
    #pragma unroll
    for (int k = 0; k < 4; ++k)
        #pragma unroll
        for (int d = 0; d < 4; ++d){
            int j2 = t + 64*k + 256*d;
            int rs = (j2 + 512) & 1023;
            float fr  = (float)(-F0D + rs*FSTEP);
            float kz2 = __fsub_rn(__fsub_rn(il2f, fc2), __fmul_rn(fr, fr));
            float kzf = sqrtf(fmaxf(kz2, 0.f));
            float2 h  = expi_from_double((double)__fmul_rn(pf, kzf));
            z[k][d] = cmulf(z[k][d], h);
        }
    r16_fft_regs<true>(B, W, t, z, a);
    const float sc = 1.0f/1024.0f;
    #pragma unroll
    for (int k = 0; k < 4; ++k)
        #pragma unroll
        for (int d = 0; d < 4; ++d){ a[k][d].x *= sc; a[k][d].y *= sc; }
    WB(); r16_st3(B, t, a);
    __syncthreads();
    for (int it = 0; it < 16; ++it){
        int rr = it*64 + (tid>>2), cc = tid & 3;
        Sz[((size_t)rr << 10) + c0 + cc] = buf[cc*SSTR + SW(rr)];
    }
}

// ---- P3 (row, IN-PLACE): inv x-FFT -> p=|u|^2, row sums, fwd x-FFT(p) ----
__global__ __launch_bounds__(256,4) void k_p3(float2* __restrict__ S,
        float* __restrict__ sumPartz, const float2* __restrict__ Wg){
    __shared__ float2 buf[4*SSTR];
    __shared__ float2 W[768];
    int tid = threadIdx.x, zz = blockIdx.y;
    int w = tid >> 6, t = tid & 63;
    load_W_wave(W, Wg, t);
    int y = blockIdx.x*4 + w;
    float2* B = buf + w*SSTR;
    float2* Sr = S + ((size_t)zz << 20) + ((size_t)y << 10);
    float2 a[4][4], z[4][4];
    #pragma unroll
    for (int k = 0; k < 4; ++k)
        #pragma unroll
        for (int q = 0; q < 4; ++q)
            a[k][q] = Sr[t + 64*k + 256*q];
    r16_fft_regs<true>(B, W, t, a, z);
    const float s2 = (1.0f/1024.0f)*(1.0f/1024.0f);
    float lsum = 0.f;
    #pragma unroll
    for (int k = 0; k < 4; ++k)
        #pragma unroll
        for (int d = 0; d < 4; ++d){
            float2 u = z[k][d];
            float p = (u.x*u.x + u.y*u.y) * s2;
            a[k][d] = make_float2(p, 0.f);
            lsum += p;
        }
    for (int o = 32; o > 0; o >>= 1) lsum += __shfl_down(lsum, o, 64);
    if (t == 0) sumPartz[zz*1024 + y] = lsum;
    WB();
    r16_fft_regs<false>(B, W, t, a, z);
    #pragma unroll
    for (int k = 0; k < 4; ++k)
        #pragma unroll
        for (int d = 0; d < 4; ++d)
            Sr[t + 64*k + 256*d] = z[k][d];
}

// ---- P4 (col, IN-PLACE, kx<=512 only): fwd y-FFT, 1/sum, diag; write half back ----
__global__ __launch_bounds__(256,4) void k_p4(float2* __restrict__ S,
        const float* __restrict__ sumPartz, const float* __restrict__ TMv,
        float* __restrict__ dpartz, const float2* __restrict__ Wg){
    __shared__ float2 buf[4*SSTR];
    __shared__ float2 W[768];
    int tid = threadIdx.x, bx = blockIdx.x, zz = blockIdx.y;
    int c0 = bx*4;
    int w = tid >> 6, t = tid & 63;
    load_W_wave(W, Wg, t);
    float2* Sz = S + ((size_t)zz << 20);
    for (int it = 0; it < 16; ++it){
        int rr = it*64 + (tid>>2), cc = tid & 3;
        int kxc = c0 + cc;           // <= 515, always in-bounds; waves >512 discarded
        buf[cc*SSTR + SW(rr)] = Sz[((size_t)rr << 10) + kxc];
    }
    // per-wave redundant total-sum reduction (overlaps staging latency)
    double sd = 0.0;
    for (int i = t; i < 1024; i += 64) sd += (double)sumPartz[zz*1024 + i];
    for (int o = 32; o > 0; o >>= 1) sd += __shfl_down(sd, o, 64);
    sd = __shfl(sd, 0, 64);
    float inv = (float)(1.0/sd);
    __syncthreads();
    int kx = c0 + w;
    float2* B = buf + w*SSTR;
    float2 a[4][4], z[4][4];
    r16_load(B, t, a);
    r16_fft_regs<false>(B, W, t, a, z);
    const float nrm = 1.0f/1048576.0f;
    float dacc = 0.f;
    const float* TMc = TMv + ((size_t)(kx <= 512 ? kx : 0) << 10);
    #pragma unroll
    for (int k = 0; k < 4; ++k)
        #pragma unroll
        for (int d = 0; d < 4; ++d){
            float2 s = z[k][d]; s.x *= inv; s.y *= inv; z[k][d] = s;
            float tmv = TMc[t + 64*k + 256*d];
            if (tmv >= 0.f){
                float dff = (s.x*s.x + s.y*s.y - tmv) * nrm;
                dacc += dff * dff;
            }
        }
    for (int o = 32; o > 0; o >>= 1) dacc += __shfl_down(dacc, o, 64);
    WB(); r16_st3(B, t, z);
    __syncthreads();
    for (int it = 0; it < 16; ++it){
        int rr = it*64 + (tid>>2), cc = tid & 3;
        int kxc = c0 + cc;
        if (kxc <= 512)
            Sz[((size_t)rr << 10) + kxc] = buf[cc*SSTR + SW(rr)];
    }
    if (t == 0 && kx <= 512){
        float wgt = (kx == 0 || kx == 512) ? 1.f : 2.f;
        dpartz[zz*1024 + kx] = dacc * wgt;
    }
}

static __device__ __forceinline__ void pair_of(int p, int& a, int& b){
    int i = 0, c = NZ-1;
    while (p >= c){ p -= c; ++i; --c; }
    a = i; b = i + 1 + p;
}

// ---- pairA (row): G rows (Hermitian mirror in kx), inv kx-FFT, write U rows ----
__global__ __launch_bounds__(256,4) void k_pairA(const float2* __restrict__ S,
        float2* __restrict__ U, int ubase, const float2* __restrict__ Wg){
    __shared__ float2 buf[4*SSTR];
    __shared__ float2 W[768];
    int tid = threadIdx.x, ug = blockIdx.y;
    int w = tid >> 6, t = tid & 63;
    load_W_wave(W, Wg, t);
    int ky = blockIdx.x*4 + w;
    int my = (1024 - ky) & 1023;
    float2* B = buf + w*SSTR;
    int u = ubase + ug;
    int pa = 2*u, pb = (2*u+1 < NPAIR) ? (2*u+1) : (NPAIR-1);
    int i1, i2, j1, j2;
    pair_of(pa, i1, i2); pair_of(pb, j1, j2);
    const float2* A1 = S + ((size_t)i1 << 20) + ((size_t)ky << 10);
    const float2* A2 = S + ((size_t)i2 << 20) + ((size_t)ky << 10);
    const float2* B1 = S + ((size_t)j1 << 20) + ((size_t)ky << 10);
    const float2* B2 = S + ((size_t)j2 << 20) + ((size_t)ky << 10);
    const float2* A1m = S + ((size_t)i1 << 20) + ((size_t)my << 10);
    const float2* A2m = S + ((size_t)i2 << 20) + ((size_t)my << 10);
    const float2* B1m = S + ((size_t)j1 << 20) + ((size_t)my << 10);
    const float2* B2m = S + ((size_t)j2 << 20) + ((size_t)my << 10);
    float2 a[4][4], z[4][4];
    #pragma unroll
    for (int k = 0; k < 4; ++k)
        #pragma unroll
        for (int q = 0; q < 4; ++q){
            int idx = t + 64*k + 256*q;
            float2 g1, g2;
            if (idx <= 512){
                float2 x1 = A1[idx], y1 = A2[idx], x2 = B1[idx], y2 = B2[idx];
                g1 = make_float2(x1.x*y1.x + x1.y*y1.y, x1.x*y1.y - x1.y*y1.x);
                g2 = make_float2(x2.x*y2.x + x2.y*y2.y, x2.x*y2.y - x2.y*y2.x);
            } else {
                int m = 1024 - idx;
                float2 x1 = A1m[m], y1 = A2m[m], x2 = B1m[m], y2 = B2m[m];
                g1 = make_float2(x1.x*y1.x + x1.y*y1.y, x1.y*y1.x - x1.x*y1.y);
                g2 = make_float2(x2.x*y2.x + x2.y*y2.y, x2.y*y2.x - x2.x*y2.y);
            }
            a[k][q] = make_float2(g1.x - g2.y, g1.y + g2.x);
        }
    r16_fft_regs<true>(B, W, t, a, z);
    const float sc = 1.0f/1024.0f;
    float2* Up = U + ((size_t)ug << 20) + ((size_t)ky << 10);
    #pragma unroll
    for (int k = 0; k < 4; ++k)
        #pragma unroll
        for (int d = 0; d < 4; ++d){
            float2 v = z[k][d];
            Up[t + 64*k + 256*d] = make_float2(v.x*sc, v.y*sc);
        }
}

// ---- pairB (col): stage cols of U, inv ky-FFT, |Re|,|Im|, per-column lse partials ----
__global__ __launch_bounds__(256,4) void k_pairB(const float2* __restrict__ U,
        float2* __restrict__ lsePart, int ubase, const float2* __restrict__ Wg){
    __shared__ float2 buf[4*SSTR];
    __shared__ float2 W[768];
    int tid = threadIdx.x, bx = blockIdx.x, ug = blockIdx.y;
    int cb = ((bx & 7) << 5) | (bx >> 3);
    int c0 = cb*4;
    int w = tid >> 6, t = tid & 63;
    int u = ubase + ug;
    load_W_wave(W, Wg, t);
    const float2* Up = U + ((size_t)ug << 20);
    for (int it = 0; it < 16; ++it){
        int rr = it*64 + (tid>>2), cc = tid & 3;
        buf[cc*SSTR + SW(rr)] = Up[((size_t)rr << 10) + c0 + cc];
    }
    __syncthreads();
    float2* B = buf + w*SSTR;
    float2 a[4][4], z[4][4];
    r16_load(B, t, a);
    r16_fft_regs<true>(B, W, t, a, z);
    const float sc = 1.0f/1024.0f;
    float m1 = -1.f, m2 = -1.f;
    #pragma unroll
    for (int k = 0; k < 4; ++k)
        #pragma unroll
        for (int d = 0; d < 4; ++d){
            float c1 = fabsf(z[k][d].x)*sc, c2 = fabsf(z[k][d].y)*sc;
            z[k][d] = make_float2(c1, c2);
            m1 = fmaxf(m1, c1); m2 = fmaxf(m2, c2);
        }
    for (int o = 32; o > 0; o >>= 1){
        m1 = fmaxf(m1, __shfl_down(m1, o, 64));
        m2 = fmaxf(m2, __shfl_down(m2, o, 64));
    }
    float M1 = __shfl(m1, 0, 64), M2 = __shfl(m2, 0, 64);
    float s1 = 0.f, s2 = 0.f;
    #pragma unroll
    for (int k = 0; k < 4; ++k)
        #pragma unroll
        for (int d = 0; d < 4; ++d){
            s1 += expf((z[k][d].x - M1) * 100.0f);
            s2 += expf((z[k][d].y - M2) * 100.0f);
        }
    for (int o = 32; o > 0; o >>= 1){
        s1 += __shfl_down(s1, o, 64);
        s2 += __shfl_down(s2, o, 64);
    }
    if (t == 0){
        int xp = c0 + w;
        lsePart[(size_t)(2*u)*1024 + xp] = make_float2(M1, s1);
        if (2*u+1 < NPAIR)
            lsePart[(size_t)(2*u+1)*1024 + xp] = make_float2(M2, s2);
    }
}

// ---- final: 10 diag sums (513 partials) + 45 off (1024 partial LSEs) ----
__global__ __launch_bounds__(256) void k_final(const float* __restrict__ dpart,
        const float2* __restrict__ lsePart, float* __restrict__ out){
    __shared__ double dred[4];
    __shared__ float fred[4];
    int b = blockIdx.x, tid = threadIdx.x;
    if (b < NZ){
        double s = (double)dpart[b*1024 + tid] + (double)dpart[b*1024 + 256 + tid];
        if (tid == 0) s += (double)dpart[b*1024 + 512];
        for (int o = 32; o > 0; o >>= 1) s += __shfl_down(s, o, 64);
        if ((tid & 63) == 0) dred[tid >> 6] = s;
        __syncthreads();
        if (tid == 0) out[b] = (float)(dred[0]+dred[1]+dred[2]+dred[3]);
    } else {
        int p = b - NZ;
        const float2* lp = lsePart + (size_t)p*1024;
        float2 v[4]; float m = -1e30f;
        #pragma unroll
        for (int c = 0; c < 4; ++c){ v[c] = lp[tid + 256*c]; m = fmaxf(m, v[c].x); }
        for (int o = 32; o > 0; o >>= 1) m = fmaxf(m, __shfl_down(m, o, 64));
        if ((tid & 63) == 0) fred[tid >> 6] = m;
        __syncthreads();
        float M = fmaxf(fmaxf(fred[0], fred[1]), fmaxf(fred[2], fred[3]));
        double s = 0.0;
        #pragma unroll
        for (int c = 0; c < 4; ++c)
            s += (double)v[c].y * (double)expf((v[c].x - M)*100.0f);
        for (int o = 32; o > 0; o >>= 1) s += __shfl_down(s, o, 64);
        if ((tid & 63) == 0) dred[tid >> 6] = s;
        __syncthreads();
        if (tid == 0)
            out[NZ + p] = (float)(30.0*(double)M + 0.3*log(dred[0]+dred[1]+dred[2]+dred[3]));
    }
}

extern "C" void kernel_launch(void* const* d_in, const int* in_sizes, int n_in,
                              void* d_out, int out_size, void* d_ws, size_t ws_size,
                              hipStream_t stream){
    const float* rlist   = (const float*)d_in[0];
    const float* xpos    = (const float*)d_in[1];
    const float* ypos    = (const float*)d_in[2];
    const float* defocus = (const float*)d_in[3];
    const float* tF      = (const float*)d_in[4];
    const float* dmask   = (const float*)d_in[5];
    float* out = (float*)d_out;

    char* ws = (char*)d_ws;
    float2* S    = (float2*)(ws);                    // 10 full planes: 83,886,080 B
    char*   tail = ws + 83886080;                    // 512 KiB small-buffer region
    float*  sumPart = (float*) (tail);               // 40,960
    float*  dpart   = (float*) (tail + 40960);       // 40,960
    float2* lsePart = (float2*)(tail + 81920);       // 368,640
    float2* Wg      = (float2*)(tail + 450560);      // 6,144
    char*   X    = ws + 83886080 + 524288;           // X region
    float*  phiA = (float*) (X);                     // 4 MiB (dead after p1)
    float*  TMv  = (float*) (X + 4194304);           // 2.1 MiB (dead after p4)
    float2* U    = (float2*)(X);                     // UB*8 MiB (alive in pair stage)

    size_t Xoff = 83886080 + 524288;
    int UB = (ws_size >= Xoff + (48ull<<20)) ? 6 : 5;

    k_prep<<<5123, 256, 0, stream>>>(rlist, xpos, ypos, tF, dmask, phiA, TMv, Wg);
    k_p1<<<dim3(256, NZ), 256, 0, stream>>>(phiA, defocus, S, Wg);
    k_p2<<<dim3(256, NZ), 256, 0, stream>>>(S, Wg);
    k_p3<<<dim3(256, NZ), 256, 0, stream>>>(S, sumPart, Wg);
    k_p4<<<dim3(129, NZ), 256, 0, stream>>>(S, sumPart, TMv, dpart, Wg);
    for (int g = 0; g < NUNIT; g += UB){
        int cnt = (NUNIT - g < UB) ? (NUNIT - g) : UB;
        k_pairA<<<dim3(256, cnt), 256, 0, stream>>>(S, U, g, Wg);
        k_pairB<<<dim3(256, cnt), 256, 0, stream>>>(U, lsePart, g, Wg);
    }
    k_final<<<NZ + NPAIR, 256, 0, stream>>>(dpart, lsePart, out);
}

// Round 7
// 524.224 us; speedup vs baseline: 1.3826x; 1.2759x over previous
//
#include <hip/hip_runtime.h>
#include <math.h>

#define NZ 10
#define NLENS 29
#define NPAIR 45
#define NUNIT 23
#define SSTR 1028               // padded wave-slice stride (float2)

static __device__ __forceinline__ float2 cmulf(float2 a, float2 b){
    return make_float2(a.x*b.x - a.y*b.y, a.x*b.y + a.y*b.x);
}
#define SW(i) ((i) ^ (((i)>>5)&31))
#define WB() __builtin_amdgcn_wave_barrier()

static constexpr double PI2   = 6.283185307179586;
static constexpr double KD    = PI2/0.00051;            // 2*pi/lambda
static constexpr double F0D   = 1.0/(2.0*(3.6/1024.0)); // 1/(2*PS)
static constexpr double FSTEP = 2.0*F0D/1023.0;
static constexpr double IL2D  = (1.0/0.00051)*(1.0/0.00051);
static constexpr double TPPID = PI2*8.74;               // 2*pi*T_PROP

// per-wave redundant W fill (768 entries; benign identical-value race, no barrier)
static __device__ __forceinline__ void load_W_wave(float2* W, const float2* Wg, int t){
    #pragma unroll
    for (int i = 0; i < 12; ++i){ int idx = t + 64*i; W[SW(idx)] = Wg[idx]; }
}

template<bool INV>
static __device__ __forceinline__ void bf4(const float2 a[4], float2 w1, float2 w2, float2 w3, float2 o[4]){
    if (INV){ w1.y = -w1.y; w2.y = -w2.y; w3.y = -w3.y; }
    float2 a1 = cmulf(a[1], w1), a2 = cmulf(a[2], w2), a3 = cmulf(a[3], w3);
    float2 t0 = make_float2(a[0].x+a2.x, a[0].y+a2.y);
    float2 t1 = make_float2(a[0].x-a2.x, a[0].y-a2.y);
    float2 t2 = make_float2(a1.x+a3.x, a1.y+a3.y);
    float2 t3 = make_float2(a1.x-a3.x, a1.y-a3.y);
    o[0] = make_float2(t0.x+t2.x, t0.y+t2.y);
    o[2] = make_float2(t0.x-t2.x, t0.y-t2.y);
    if (!INV){
        o[1] = make_float2(t1.x + t3.y, t1.y - t3.x);
        o[3] = make_float2(t1.x - t3.y, t1.y + t3.x);
    } else {
        o[1] = make_float2(t1.x - t3.y, t1.y + t3.x);
        o[3] = make_float2(t1.x + t3.y, t1.y - t3.x);
    }
}
template<bool INV>
static __device__ __forceinline__ void bf4nt(const float2 a[4], float2 o[4]){
    float2 t0 = make_float2(a[0].x+a[2].x, a[0].y+a[2].y);
    float2 t1 = make_float2(a[0].x-a[2].x, a[0].y-a[2].y);
    float2 t2 = make_float2(a[1].x+a[3].x, a[1].y+a[3].y);
    float2 t3 = make_float2(a[1].x-a[3].x, a[1].y-a[3].y);
    o[0] = make_float2(t0.x+t2.x, t0.y+t2.y);
    o[2] = make_float2(t0.x-t2.x, t0.y-t2.y);
    if (!INV){
        o[1] = make_float2(t1.x + t3.y, t1.y - t3.x);
        o[3] = make_float2(t1.x - t3.y, t1.y + t3.x);
    } else {
        o[1] = make_float2(t1.x - t3.y, t1.y + t3.x);
        o[3] = make_float2(t1.x + t3.y, t1.y - t3.x);
    }
}

// ===== radix-16 1024-pt Stockham, ONE WAVE per FFT, wave-private LDS slice =====
static __device__ __forceinline__ void r16_load(const float2* B, int t, float2 a[4][4]){
    #pragma unroll
    for (int k = 0; k < 4; ++k)
        #pragma unroll
        for (int q = 0; q < 4; ++q)
            a[k][q] = B[SW(t + 64*k + 256*q)];
}
template<bool INV>
static __device__ __forceinline__ void r16_s14(const float2 a[4][4], const float2* W, float2 z[4][4]){
    float2 y[4][4];
    #pragma unroll
    for (int k = 0; k < 4; ++k) bf4nt<INV>(a[k], y[k]);
    #pragma unroll
    for (int i = 0; i < 4; ++i){
        float2 b[4] = { y[0][i], y[1][i], y[2][i], y[3][i] };
        bf4<INV>(b, W[SW(64*i)], W[SW(128*i)], W[SW(192*i)], z[i]);
    }
}
static __device__ __forceinline__ void r16_st1(float2* B, int t, const float2 z[4][4]){
    #pragma unroll
    for (int i = 0; i < 4; ++i)
        #pragma unroll
        for (int d = 0; d < 4; ++d)
            B[SW(16*t + i + 4*d)] = z[i][d];
}
template<bool INV>
static __device__ __forceinline__ void r16_s16_64(const float2 a[4][4], const float2* W, int t, float2 z[4][4]){
    int mt = t & 15;
    float2 y[4][4];
    float2 w1 = W[SW(16*mt)], w2 = W[SW(32*mt)], w3 = W[SW(48*mt)];
    #pragma unroll
    for (int k = 0; k < 4; ++k) bf4<INV>(a[k], w1, w2, w3, y[k]);
    #pragma unroll
    for (int n = 0; n < 4; ++n){
        int m2 = mt + 16*n;
        float2 b[4] = { y[0][n], y[1][n], y[2][n], y[3][n] };
        bf4<INV>(b, W[SW(4*m2)], W[SW(8*m2)], W[SW(12*m2)], z[n]);
    }
}
static __device__ __forceinline__ void r16_st2(float2* B, int t, const float2 z[4][4]){
    int base = 256*(t>>4) + (t&15);
    #pragma unroll
    for (int n = 0; n < 4; ++n)
        #pragma unroll
        for (int d = 0; d < 4; ++d)
            B[SW(base + 16*n + 64*d)] = z[n][d];
}
template<bool INV>
static __device__ __forceinline__ void r16_s256(const float2 a[4][4], const float2* W, int t, float2 z[4][4]){
    #pragma unroll
    for (int k = 0; k < 4; ++k){
        int j = t + 64*k;
        bf4<INV>(a[k], W[SW(j)], W[SW(2*j)], W[SW(3*j)], z[k]);
    }
}
static __device__ __forceinline__ void r16_st3(float2* B, int t, const float2 z[4][4]){
    #pragma unroll
    for (int k = 0; k < 4; ++k)
        #pragma unroll
        for (int d = 0; d < 4; ++d)
            B[SW(t + 64*k + 256*d)] = z[k][d];
}
// input a[k][q] = element t+64k+256q; output z[k][d] = element t+64k+256d
template<bool INV>
static __device__ void r16_fft_regs(float2* B, const float2* W, int t, float2 a[4][4], float2 z[4][4]){
    float2 b[4][4];
    r16_s14<INV>(a, W, z);
    WB(); r16_st1(B, t, z); WB();
    r16_load(B, t, b); r16_s16_64<INV>(b, W, t, z);
    WB(); r16_st2(B, t, z); WB();
    r16_load(B, t, b); r16_s256<INV>(b, W, t, z);
}

static __device__ __forceinline__ float2 expi_from_double(double ph){
    double t = ph * (1.0/PI2);
    t -= floor(t);
    float th = (float)(t * PI2);
    float s, c; sincosf(th, &s, &c);
    return make_float2(c, s);
}

// ---- prep: lens phase+aperture (sign-packed), masked-tF half transpose, twiddles ----
__global__ __launch_bounds__(256) void k_prep(const float* __restrict__ rlist,
        const float* __restrict__ xpos, const float* __restrict__ ypos,
        const float* __restrict__ tF, const float* __restrict__ dm,
        float* __restrict__ phiA, float* __restrict__ TMv, float2* __restrict__ Wg){
    __shared__ float Tt[32][33];
    int b = blockIdx.x, tid = threadIdx.x;
    if (b < 4096){
        int idx = b*256 + tid;
        int r = idx >> 10, c = idx & 1023;
        float x = (float)(-1.8 + c*(3.6/1023.0));
        float y = (float)(-1.8 + r*(3.6/1023.0));
        const float ca2 = (float)(0.165*0.165);
        float Ts = 0.f; int any = 0;
        for (int l = 0; l < NLENS; ++l){
            float dx = x - xpos[l], dy = y - ypos[l];
            float d2 = dx*dx + dy*dy;
            if (d2 <= ca2){
                float rr = rlist[l];
                Ts += rr - sqrtf(fmaxf(rr*rr - d2, 1e-12f));
                any = 1;
            }
        }
        int ap = any && (x*x + y*y) <= 0.81f;
        float phi = (float)(KD*(1.515 - 1.0)) * Ts;
        phiA[idx] = ap ? phi : -1.0f;
    } else if (b < 5120){
        int tb = b - 4096;
        int bx = tb & 31, by = tb >> 5;
        int tx = tid & 31, ty = tid >> 5;   // 32 x 8
        #pragma unroll
        for (int j = 0; j < 4; ++j){
            int r = by*32 + ty + 8*j, c = bx*32 + tx;
            float tv = tF[(size_t)r*1024 + c];
            float mv = dm[(size_t)r*1024 + c];
            Tt[ty+8*j][tx] = (mv > 0.f) ? tv : -1.0f;
        }
        __syncthreads();
        #pragma unroll
        for (int j = 0; j < 4; ++j){
            int c = bx*32 + ty + 8*j, r = by*32 + tx;
            if (c <= 512) TMv[(size_t)c*1024 + r] = Tt[tx][ty+8*j];
        }
    } else {
        int t = (b-5120)*256 + tid;   // 3 blocks -> 768 entries
        float a = (float)((double)t * (-PI2/1024.0));
        float s, c; sincosf(a, &s, &c);
        Wg[t] = make_float2(c, s);
    }
}

// ---- P1 (row): gen U1 rows -> fwd x-FFT -> write S[y][kx] rows coalesced ----
__global__ __launch_bounds__(256) void k_p1(const float* __restrict__ phiA,
        const float* __restrict__ defocus, float2* __restrict__ S,
        const float2* __restrict__ Wg){
    __shared__ float2 buf[4*SSTR];
    __shared__ float2 W[768];
    int tid = threadIdx.x, zz = blockIdx.y;
    int w = tid >> 6, t = tid & 63;
    load_W_wave(W, Wg, t);
    int row = blockIdx.x*4 + w;
    float2* B = buf + w*SSTR;
    float zf = defocus[zz];
    float y  = (float)(-1.8 + row*(3.6/1023.0));
    const float KF = (float)KD;
    const float* pha = phiA + ((size_t)row << 10);
    float2 a[4][4], z[4][4];
    #pragma unroll
    for (int k = 0; k < 4; ++k)
        #pragma unroll
        for (int q = 0; q < 4; ++q){
            int idx = t + 64*k + 256*q;
            float x = (float)(-1.8 + idx*(3.6/1023.0));
            float v = pha[idx];
            float2 uu = make_float2(0.f, 0.f);
            if (v >= 0.f){
                float qq = x*x + y*y;
                float phi_in = (KF*qq) / (2.0f*zf);
                uu = expi_from_double((double)(phi_in + v));
            }
            a[k][q] = uu;
        }
    r16_fft_regs<false>(B, W, t, a, z);
    float2* Sr = S + ((size_t)zz << 20) + ((size_t)row << 10);
    #pragma unroll
    for (int k = 0; k < 4; ++k)
        #pragma unroll
        for (int d = 0; d < 4; ++d)
            Sr[t + 64*k + 256*d] = z[k][d];
}

// ---- P2 (col, IN-PLACE): stage cols, fwd y-FFT, *H(fly), inv y-FFT, stage-out ----
__global__ __launch_bounds__(256) void k_p2(float2* __restrict__ S,
        const float2* __restrict__ Wg){
    __shared__ float2 buf[4*SSTR];
    __shared__ float2 W[768];
    int tid = threadIdx.x, bx = blockIdx.x, zz = blockIdx.y;
    int cb = ((bx & 7) << 5) | (bx >> 3);
    int c0 = cb*4;
    int w = tid >> 6, t = tid & 63;
    load_W_wave(W, Wg, t);
    float2* Sz = S + ((size_t)zz << 20);
    for (int it = 0; it < 16; ++it){
        int rr = it*64 + (tid>>2), cc = tid & 3;
        buf[cc*SSTR + SW(rr)] = Sz[((size_t)rr << 10) + c0 + cc];
    }
    __syncthreads();
    int kx = c0 + w;
    float2* B = buf + w*SSTR;
    float2 a[4][4], z[4][4];
    r16_load(B, t, a);
    r16_fft_regs<false>(B, W, t, a, z);
    // H on the fly (column term wave-uniform)
    int cs = (kx + 512) & 1023;
    float fc  = (float)(-F0D + cs*FSTEP);
    float fc2 = __fmul_rn(fc, fc);
    const float il2f = (float)IL2D, pf = (float)TPPID;
    #pragma unroll
    for (int k = 0; k < 4; ++k)
        #pragma unroll
        for (int d = 0; d < 4; ++d){
            int j2 = t + 64*k + 256*d;
            int rs = (j2 + 512) & 1023;
            float fr  = (float)(-F0D + rs*FSTEP);
            float kz2 = __fsub_rn(__fsub_rn(il2f, fc2), __fmul_rn(fr, fr));
            float kzf = sqrtf(fmaxf(kz2, 0.f));
            float2 h  = expi_from_double((double)__fmul_rn(pf, kzf));
            z[k][d] = cmulf(z[k][d], h);
        }
    r16_fft_regs<true>(B, W, t, z, a);
    const float sc = 1.0f/1024.0f;
    #pragma unroll
    for (int k = 0; k < 4; ++k)
        #pragma unroll
        for (int d = 0; d < 4; ++d){ a[k][d].x *= sc; a[k][d].y *= sc; }
    WB(); r16_st3(B, t, a);
    __syncthreads();
    for (int it = 0; it < 16; ++it){
        int rr = it*64 + (tid>>2), cc = tid & 3;
        Sz[((size_t)rr << 10) + c0 + cc] = buf[cc*SSTR + SW(rr)];
    }
}

// ---- P3 (row, IN-PLACE): inv x-FFT -> p=|u|^2, row sums, fwd x-FFT(p) ----
__global__ __launch_bounds__(256) void k_p3(float2* __restrict__ S,
        float* __restrict__ sumPartz, const float2* __restrict__ Wg){
    __shared__ float2 buf[4*SSTR];
    __shared__ float2 W[768];
    int tid = threadIdx.x, zz = blockIdx.y;
    int w = tid >> 6, t = tid & 63;
    load_W_wave(W, Wg, t);
    int y = blockIdx.x*4 + w;
    float2* B = buf + w*SSTR;
    float2* Sr = S + ((size_t)zz << 20) + ((size_t)y << 10);
    float2 a[4][4], z[4][4];
    #pragma unroll
    for (int k = 0; k < 4; ++k)
        #pragma unroll
        for (int q = 0; q < 4; ++q)
            a[k][q] = Sr[t + 64*k + 256*q];
    r16_fft_regs<true>(B, W, t, a, z);
    const float s2 = (1.0f/1024.0f)*(1.0f/1024.0f);
    float lsum = 0.f;
    #pragma unroll
    for (int k = 0; k < 4; ++k)
        #pragma unroll
        for (int d = 0; d < 4; ++d){
            float2 u = z[k][d];
            float p = (u.x*u.x + u.y*u.y) * s2;
            a[k][d] = make_float2(p, 0.f);
            lsum += p;
        }
    for (int o = 32; o > 0; o >>= 1) lsum += __shfl_down(lsum, o, 64);
    if (t == 0) sumPartz[zz*1024 + y] = lsum;
    WB();
    r16_fft_regs<false>(B, W, t, a, z);
    #pragma unroll
    for (int k = 0; k < 4; ++k)
        #pragma unroll
        for (int d = 0; d < 4; ++d)
            Sr[t + 64*k + 256*d] = z[k][d];
}

// ---- P4 (col, IN-PLACE, kx<=512 only): fwd y-FFT, 1/sum, diag; write half back ----
__global__ __launch_bounds__(256) void k_p4(float2* __restrict__ S,
        const float* __restrict__ sumPartz, const float* __restrict__ TMv,
        float* __restrict__ dpartz, const float2* __restrict__ Wg){
    __shared__ float2 buf[4*SSTR];
    __shared__ float2 W[768];
    int tid = threadIdx.x, bx = blockIdx.x, zz = blockIdx.y;
    int c0 = bx*4;
    int w = tid >> 6, t = tid & 63;
    load_W_wave(W, Wg, t);
    float2* Sz = S + ((size_t)zz << 20);
    for (int it = 0; it < 16; ++it){
        int rr = it*64 + (tid>>2), cc = tid & 3;
        int kxc = c0 + cc;           // <= 515, always in-bounds; waves >512 discarded
        buf[cc*SSTR + SW(rr)] = Sz[((size_t)rr << 10) + kxc];
    }
    // per-wave redundant total-sum reduction (overlaps staging latency)
    double sd = 0.0;
    for (int i = t; i < 1024; i += 64) sd += (double)sumPartz[zz*1024 + i];
    for (int o = 32; o > 0; o >>= 1) sd += __shfl_down(sd, o, 64);
    sd = __shfl(sd, 0, 64);
    float inv = (float)(1.0/sd);
    __syncthreads();
    int kx = c0 + w;
    float2* B = buf + w*SSTR;
    float2 a[4][4], z[4][4];
    r16_load(B, t, a);
    r16_fft_regs<false>(B, W, t, a, z);
    const float nrm = 1.0f/1048576.0f;
    float dacc = 0.f;
    const float* TMc = TMv + ((size_t)(kx <= 512 ? kx : 0) << 10);
    #pragma unroll
    for (int k = 0; k < 4; ++k)
        #pragma unroll
        for (int d = 0; d < 4; ++d){
            float2 s = z[k][d]; s.x *= inv; s.y *= inv; z[k][d] = s;
            float tmv = TMc[t + 64*k + 256*d];
            if (tmv >= 0.f){
                float dff = (s.x*s.x + s.y*s.y - tmv) * nrm;
                dacc += dff * dff;
            }
        }
    for (int o = 32; o > 0; o >>= 1) dacc += __shfl_down(dacc, o, 64);
    WB(); r16_st3(B, t, z);
    __syncthreads();
    for (int it = 0; it < 16; ++it){
        int rr = it*64 + (tid>>2), cc = tid & 3;
        int kxc = c0 + cc;
        if (kxc <= 512)
            Sz[((size_t)rr << 10) + kxc] = buf[cc*SSTR + SW(rr)];
    }
    if (t == 0 && kx <= 512){
        float wgt = (kx == 0 || kx == 512) ? 1.f : 2.f;
        dpartz[zz*1024 + kx] = dacc * wgt;
    }
}

static __device__ __forceinline__ void pair_of(int p, int& a, int& b){
    int i = 0, c = NZ-1;
    while (p >= c){ p -= c; ++i; --c; }
    a = i; b = i + 1 + p;
}

// ---- pairA (row): G rows (Hermitian mirror in kx), inv kx-FFT, write U rows ----
__global__ __launch_bounds__(256) void k_pairA(const float2* __restrict__ S,
        float2* __restrict__ U, int ubase, const float2* __restrict__ Wg){
    __shared__ float2 buf[4*SSTR];
    __shared__ float2 W[768];
    int tid = threadIdx.x, ug = blockIdx.y;
    int w = tid >> 6, t = tid & 63;
    load_W_wave(W, Wg, t);
    int ky = blockIdx.x*4 + w;
    int my = (1024 - ky) & 1023;
    float2* B = buf + w*SSTR;
    int u = ubase + ug;
    int pa = 2*u, pb = (2*u+1 < NPAIR) ? (2*u+1) : (NPAIR-1);
    int i1, i2, j1, j2;
    pair_of(pa, i1, i2); pair_of(pb, j1, j2);
    const float2* A1 = S + ((size_t)i1 << 20) + ((size_t)ky << 10);
    const float2* A2 = S + ((size_t)i2 << 20) + ((size_t)ky << 10);
    const float2* B1 = S + ((size_t)j1 << 20) + ((size_t)ky << 10);
    const float2* B2 = S + ((size_t)j2 << 20) + ((size_t)ky << 10);
    const float2* A1m = S + ((size_t)i1 << 20) + ((size_t)my << 10);
    const float2* A2m = S + ((size_t)i2 << 20) + ((size_t)my << 10);
    const float2* B1m = S + ((size_t)j1 << 20) + ((size_t)my << 10);
    const float2* B2m = S + ((size_t)j2 << 20) + ((size_t)my << 10);
    float2 a[4][4], z[4][4];
    #pragma unroll
    for (int k = 0; k < 4; ++k)
        #pragma unroll
        for (int q = 0; q < 4; ++q){
            int idx = t + 64*k + 256*q;
            float2 g1, g2;
            if (idx <= 512){
                float2 x1 = A1[idx], y1 = A2[idx], x2 = B1[idx], y2 = B2[idx];
                g1 = make_float2(x1.x*y1.x + x1.y*y1.y, x1.x*y1.y - x1.y*y1.x);
                g2 = make_float2(x2.x*y2.x + x2.y*y2.y, x2.x*y2.y - x2.y*y2.x);
            } else {
                int m = 1024 - idx;
                float2 x1 = A1m[m], y1 = A2m[m], x2 = B1m[m], y2 = B2m[m];
                g1 = make_float2(x1.x*y1.x + x1.y*y1.y, x1.y*y1.x - x1.x*y1.y);
                g2 = make_float2(x2.x*y2.x + x2.y*y2.y, x2.y*y2.x - x2.x*y2.y);
            }
            a[k][q] = make_float2(g1.x - g2.y, g1.y + g2.x);
        }
    r16_fft_regs<true>(B, W, t, a, z);
    const float sc = 1.0f/1024.0f;
    float2* Up = U + ((size_t)ug << 20) + ((size_t)ky << 10);
    #pragma unroll
    for (int k = 0; k < 4; ++k)
        #pragma unroll
        for (int d = 0; d < 4; ++d){
            float2 v = z[k][d];
            Up[t + 64*k + 256*d] = make_float2(v.x*sc, v.y*sc);
        }
}

// ---- pairB (col): stage cols of U, inv ky-FFT, |Re|,|Im|, per-column lse partials ----
__global__ __launch_bounds__(256) void k_pairB(const float2* __restrict__ U,
        float2* __restrict__ lsePart, int ubase, const float2* __restrict__ Wg){
    __shared__ float2 buf[4*SSTR];
    __shared__ float2 W[768];
    int tid = threadIdx.x, bx = blockIdx.x, ug = blockIdx.y;
    int cb = ((bx & 7) << 5) | (bx >> 3);
    int c0 = cb*4;
    int w = tid >> 6, t = tid & 63;
    int u = ubase + ug;
    load_W_wave(W, Wg, t);
    const float2* Up = U + ((size_t)ug << 20);
    for (int it = 0; it < 16; ++it){
        int rr = it*64 + (tid>>2), cc = tid & 3;
        buf[cc*SSTR + SW(rr)] = Up[((size_t)rr << 10) + c0 + cc];
    }
    __syncthreads();
    float2* B = buf + w*SSTR;
    float2 a[4][4], z[4][4];
    r16_load(B, t, a);
    r16_fft_regs<true>(B, W, t, a, z);
    const float sc = 1.0f/1024.0f;
    float m1 = -1.f, m2 = -1.f;
    #pragma unroll
    for (int k = 0; k < 4; ++k)
        #pragma unroll
        for (int d = 0; d < 4; ++d){
            float c1 = fabsf(z[k][d].x)*sc, c2 = fabsf(z[k][d].y)*sc;
            z[k][d] = make_float2(c1, c2);
            m1 = fmaxf(m1, c1); m2 = fmaxf(m2, c2);
        }
    for (int o = 32; o > 0; o >>= 1){
        m1 = fmaxf(m1, __shfl_down(m1, o, 64));
        m2 = fmaxf(m2, __shfl_down(m2, o, 64));
    }
    float M1 = __shfl(m1, 0, 64), M2 = __shfl(m2, 0, 64);
    float s1 = 0.f, s2 = 0.f;
    #pragma unroll
    for (int k = 0; k < 4; ++k)
        #pragma unroll
        for (int d = 0; d < 4; ++d){
            s1 += expf((z[k][d].x - M1) * 100.0f);
            s2 += expf((z[k][d].y - M2) * 100.0f);
        }
    for (int o = 32; o > 0; o >>= 1){
        s1 += __shfl_down(s1, o, 64);
        s2 += __shfl_down(s2, o, 64);
    }
    if (t == 0){
        int xp = c0 + w;
        lsePart[(size_t)(2*u)*1024 + xp] = make_float2(M1, s1);
        if (2*u+1 < NPAIR)
            lsePart[(size_t)(2*u+1)*1024 + xp] = make_float2(M2, s2);
    }
}

// ---- final: 10 diag sums (513 partials) + 45 off (1024 partial LSEs) ----
__global__ __launch_bounds__(256) void k_final(const float* __restrict__ dpart,
        const float2* __restrict__ lsePart, float* __restrict__ out){
    __shared__ double dred[4];
    __shared__ float fred[4];
    int b = blockIdx.x, tid = threadIdx.x;
    if (b < NZ){
        double s = (double)dpart[b*1024 + tid] + (double)dpart[b*1024 + 256 + tid];
        if (tid == 0) s += (double)dpart[b*1024 + 512];
        for (int o = 32; o > 0; o >>= 1) s += __shfl_down(s, o, 64);
        if ((tid & 63) == 0) dred[tid >> 6] = s;
        __syncthreads();
        if (tid == 0) out[b] = (float)(dred[0]+dred[1]+dred[2]+dred[3]);
    } else {
        int p = b - NZ;
        const float2* lp = lsePart + (size_t)p*1024;
        float2 v[4]; float m = -1e30f;
        #pragma unroll
        for (int c = 0; c < 4; ++c){ v[c] = lp[tid + 256*c]; m = fmaxf(m, v[c].x); }
        for (int o = 32; o > 0; o >>= 1) m = fmaxf(m, __shfl_down(m, o, 64));
        if ((tid & 63) == 0) fred[tid >> 6] = m;
        __syncthreads();
        float M = fmaxf(fmaxf(fred[0], fred[1]), fmaxf(fred[2], fred[3]));
        double s = 0.0;
        #pragma unroll
        for (int c = 0; c < 4; ++c)
            s += (double)v[c].y * (double)expf((v[c].x - M)*100.0f);
        for (int o = 32; o > 0; o >>= 1) s += __shfl_down(s, o, 64);
        if ((tid & 63) == 0) dred[tid >> 6] = s;
        __syncthreads();
        if (tid == 0)
            out[NZ + p] = (float)(30.0*(double)M + 0.3*log(dred[0]+dred[1]+dred[2]+dred[3]));
    }
}

extern "C" void kernel_launch(void* const* d_in, const int* in_sizes, int n_in,
                              void* d_out, int out_size, void* d_ws, size_t ws_size,
                              hipStream_t stream){
    const float* rlist   = (const float*)d_in[0];
    const float* xpos    = (const float*)d_in[1];
    const float* ypos    = (const float*)d_in[2];
    const float* defocus = (const float*)d_in[3];
    const float* tF      = (const float*)d_in[4];
    const float* dmask   = (const float*)d_in[5];
    float* out = (float*)d_out;

    char* ws = (char*)d_ws;
    float2* S    = (float2*)(ws);                    // 10 full planes: 83,886,080 B
    char*   tail = ws + 83886080;                    // 512 KiB small-buffer region
    float*  sumPart = (float*) (tail);               // 40,960
    float*  dpart   = (float*) (tail + 40960);       // 40,960
    float2* lsePart = (float2*)(tail + 81920);       // 368,640
    float2* Wg      = (float2*)(tail + 450560);      // 6,144
    char*   X    = ws + 83886080 + 524288;           // X region
    float*  phiA = (float*) (X);                     // 4 MiB (dead after p1)
    float*  TMv  = (float*) (X + 4194304);           // 2.1 MiB (dead after p4)
    float2* U    = (float2*)(X);                     // UB*8 MiB (alive in pair stage)

    size_t Xoff = 83886080 + 524288;
    int UB = (ws_size >= Xoff + (48ull<<20)) ? 6 : 5;

    k_prep<<<5123, 256, 0, stream>>>(rlist, xpos, ypos, tF, dmask, phiA, TMv, Wg);
    k_p1<<<dim3(256, NZ), 256, 0, stream>>>(phiA, defocus, S, Wg);
    k_p2<<<dim3(256, NZ), 256, 0, stream>>>(S, Wg);
    k_p3<<<dim3(256, NZ), 256, 0, stream>>>(S, sumPart, Wg);
    k_p4<<<dim3(129, NZ), 256, 0, stream>>>(S, sumPart, TMv, dpart, Wg);
    for (int g = 0; g < NUNIT; g += UB){
        int cnt = (NUNIT - g < UB) ? (NUNIT - g) : UB;
        k_pairA<<<dim3(256, cnt), 256, 0, stream>>>(S, U, g, Wg);
        k_pairB<<<dim3(256, cnt), 256, 0, stream>>>(U, lsePart, g, Wg);
    }
    k_final<<<NZ + NPAIR, 256, 0, stream>>>(dpart, lsePart, out);
}